// Round 7
// baseline (482.396 us; speedup 1.0000x reference)
//
#include <hip/hip_runtime.h>
#include <hip/hip_fp16.h>
#include <math.h>

#define EPS 1e-20f
#define NPT 256
#define BB  512

// ---- complex float2 helpers ----
__device__ __forceinline__ float2 cadd(float2 a, float2 b){ return make_float2(a.x+b.x, a.y+b.y); }
__device__ __forceinline__ float2 csub(float2 a, float2 b){ return make_float2(a.x-b.x, a.y-b.y); }
__device__ __forceinline__ float2 cmul(float2 a, float2 b){ return make_float2(a.x*b.x - a.y*b.y, a.x*b.y + a.y*b.x); }
__device__ __forceinline__ float2 cmulc(float2 a, float c, float s){ return make_float2(a.x*c - a.y*s, a.x*s + a.y*c); }
__device__ __forceinline__ float2 cmulmi(float2 a){ return make_float2(a.y, -a.x); }   // * (-i)

__device__ __forceinline__ void bfly4(float2& c0, float2& c1, float2& c2, float2& c3) {
    float2 s0 = cadd(c0, c2), s1 = cadd(c1, c3);
    float2 d0 = csub(c0, c2), d1 = cmulmi(csub(c1, c3));
    c0 = cadd(s0, s1); c1 = cadd(d0, d1); c2 = csub(s0, s1); c3 = csub(d0, d1);
}

#define C16_1 0.9238795325112867f
#define S16_1 (-0.3826834323650898f)
#define C16_2 0.7071067811865476f
#define S16_2 (-0.7071067811865476f)
#define C16_3 0.3826834323650898f
#define S16_3 (-0.9238795325112867f)
#define C16_6 (-0.7071067811865476f)
#define S16_6 (-0.7071067811865476f)
#define C16_9 (-0.9238795325112867f)
#define S16_9 0.3826834323650898f

// in-place 16-pt DIF DFT; position p ends up holding frequency r4(p)=4(p&3)+(p>>2)
__device__ __forceinline__ void dft16(float2* x) {
    bfly4(x[0], x[4], x[8], x[12]);
    bfly4(x[1], x[5], x[9], x[13]);
    x[5]  = cmulc(x[5],  C16_1, S16_1);
    x[9]  = cmulc(x[9],  C16_2, S16_2);
    x[13] = cmulc(x[13], C16_3, S16_3);
    bfly4(x[2], x[6], x[10], x[14]);
    x[6]  = cmulc(x[6],  C16_2, S16_2);
    x[10] = cmulmi(x[10]);
    x[14] = cmulc(x[14], C16_6, S16_6);
    bfly4(x[3], x[7], x[11], x[15]);
    x[7]  = cmulc(x[7],  C16_3, S16_3);
    x[11] = cmulc(x[11], C16_6, S16_6);
    x[15] = cmulc(x[15], C16_9, S16_9);
    bfly4(x[0],  x[1],  x[2],  x[3]);
    bfly4(x[4],  x[5],  x[6],  x[7]);
    bfly4(x[8],  x[9],  x[10], x[11]);
    bfly4(x[12], x[13], x[14], x[15]);
}

#define R4C(p) ((((p) & 3) << 2) | ((p) >> 2))

// full per-row pipeline: gate -> inner dft16 -> shfl transpose -> twiddle -> outer dft16
__device__ __forceinline__ void compute_row(float2* x, const float2* El,
                                            int i, int l, float2 w1) {
    // gate: x[n1] = E[16n1+l] * E[(16n1+l-i)&255]
    #pragma unroll
    for (int n1 = 0; n1 < 16; ++n1) {
        int j = 16 * n1 + l;
        x[n1] = cmul(El[j], El[(j - i) & 255]);
    }
    dft16(x);
    // 16x16 transpose across the 16-lane group, in-register shfl butterfly
    #pragma unroll
    for (int s = 1; s <= 8; s <<= 1) {
        const bool hi = (l & s) != 0;
        #pragma unroll
        for (int j0 = 0; j0 < 16; ++j0) {
            if (j0 & s) continue;
            const int j1 = j0 | s;
            float2 give = hi ? x[j0] : x[j1];
            float2 got;
            got.x = __shfl_xor(give.x, s, 64);
            got.y = __shfl_xor(give.y, s, 64);
            x[j0] = hi ? got : x[j0];
            x[j1] = hi ? x[j1] : got;
        }
    }
    // twiddle W256^{k1*n2}: powers recomputed from w1
    {
        float2 w2 = cmul(w1, w1), w3 = cmul(w2, w1);
        float2 w4 = cmul(w2, w2), w8 = cmul(w4, w4), w12 = cmul(w8, w4);
        x[1]  = cmul(x[1],  w1);
        x[2]  = cmul(x[2],  w2);
        x[3]  = cmul(x[3],  w3);
        x[4]  = cmul(x[4],  w4);
        x[5]  = cmul(cmul(x[5],  w1), w4);
        x[6]  = cmul(cmul(x[6],  w2), w4);
        x[7]  = cmul(cmul(x[7],  w3), w4);
        x[8]  = cmul(x[8],  w8);
        x[9]  = cmul(cmul(x[9],  w1), w8);
        x[10] = cmul(cmul(x[10], w2), w8);
        x[11] = cmul(cmul(x[11], w3), w8);
        x[12] = cmul(x[12], w12);
        x[13] = cmul(cmul(x[13], w1), w12);
        x[14] = cmul(cmul(x[14], w2), w12);
        x[15] = cmul(cmul(x[15], w3), w12);
    }
    dft16(x);
}

// ---------------- fused kernel: one block per batch ----------------
// 1024 threads = 64 groups of 16 lanes; each group does 4 rows.
// vs round 6: Ibuf halved (rows for r=0,1 only -> 69.6KB); r=2,3 rows kept
// in 16 persistent VGPRs as packed half2 (static indices). LDS 71.7KB ->
// 2 blocks/CU = 32 waves/CU (was 16), all 512 blocks co-resident in 1 round.
// r-loops stay `unroll 1` (round 1-5 lesson: full unroll -> interleave -> spill).
__global__ __launch_bounds__(1024) void k_fused(const float* __restrict__ xin,
                                                float* __restrict__ out) {
    __shared__ float2 El[256];
    __shared__ __align__(16) __half Ibuf[128 * 272];   // out rows 128..255 (local row i)
    __shared__ float wmax[16];

    const int tid = threadIdx.x;
    const int G   = tid >> 4;         // 0..63
    const int l   = tid & 15;
    const int b   = blockIdx.x;

    if (tid < 256)
        El[tid] = make_float2(xin[b * 512 + tid], xin[b * 512 + 256 + tid]);
    __syncthreads();

    const int k1 = R4C(l);
    float sn, cs;
    __sincosf(-0.024543692606170259f * (float)k1, &sn, &cs);   // -2pi/256 * k1
    const float2 w1 = make_float2(cs, sn);
    const int v = 127 - k1;
    float mx = 0.0f;
    float2 x[16];

    // ---- loop A: r=0,1 -> I scattered to Ibuf (out rows 128..255) ----
    #pragma unroll 1
    for (int r = 0; r < 2; ++r) {
        const int i = (r << 6) + G;            // 0..127; out row = i^128 = 128+i
        compute_row(x, El, i, l, w1);
        __half* irow = Ibuf + i * 272;
        #pragma unroll
        for (int p2 = 0; p2 < 16; ++p2) {
            float I = x[p2].x * x[p2].x + x[p2].y * x[p2].y;
            mx = fmaxf(mx, I);
            irow[(v - 16 * R4C(p2)) & 255] = __float2half_rn(I * 0.000244140625f);
        }
    }

    // ---- loop B: r=2,3 -> I packed in registers (out rows 0..127) ----
    __half2 hA[8], hB[8];
    #pragma unroll 1
    for (int r2 = 0; r2 < 2; ++r2) {
        const int i = ((r2 + 2) << 6) + G;     // 128..255; out row = i^128 = i-128
        compute_row(x, El, i, l, w1);
        __half2 hc[8];
        #pragma unroll
        for (int q = 0; q < 8; ++q) {
            float I0 = x[2 * q].x     * x[2 * q].x     + x[2 * q].y     * x[2 * q].y;
            float I1 = x[2 * q + 1].x * x[2 * q + 1].x + x[2 * q + 1].y * x[2 * q + 1].y;
            mx = fmaxf(mx, fmaxf(I0, I1));
            hc[q] = __floats2half2_rn(I0 * 0.000244140625f, I1 * 0.000244140625f);
        }
        if (r2 == 0) {
            #pragma unroll
            for (int q = 0; q < 8; ++q) hA[q] = hc[q];
        } else {
            #pragma unroll
            for (int q = 0; q < 8; ++q) hB[q] = hc[q];
        }
    }

    // ---- block-level max ----
    #pragma unroll
    for (int off = 32; off; off >>= 1) mx = fmaxf(mx, __shfl_xor(mx, off, 64));
    if ((tid & 63) == 0) wmax[tid >> 6] = mx;
    __syncthreads();   // fences Ibuf + wmax
    float bm = wmax[0];
    #pragma unroll
    for (int w = 1; w < 16; ++w) bm = fmaxf(bm, wmax[w]);
    const float inv = 4096.0f / fmaxf(bm, EPS);   // undo 2^-12 and normalize

    const size_t obase = ((size_t)b << 16);

    // ---- epilogue 1: Ibuf -> out rows 128..255, coalesced float4 ----
    const int l6 = tid & 63, w = tid >> 6;
    #pragma unroll 4
    for (int j2 = 0; j2 < 8; ++j2) {
        const int lrow = 16 * j2 + w;                       // 0..127
        float2 raw = *(const float2*)(Ibuf + lrow * 272 + 4 * l6);   // 4 halves
        float2 a = __half22float2(*(__half2*)&raw.x);
        float2 c = __half22float2(*(__half2*)&raw.y);
        float4 o = make_float4(a.x * inv, a.y * inv, c.x * inv, c.y * inv);
        *(float4*)&out[obase + (size_t)(128 + lrow) * 256 + 4 * l6] = o;
    }

    // ---- epilogue 2: registers -> out rows 0..127 (row G and 64+G) ----
    // scattered 4B stores; full row covered by the group's 16 lanes x 16 p2
    // in tight sequence -> L2 merges (round-6 counters cleared scatter of blame)
    {
        float* rowA = out + obase + (size_t)G * 256;          // from hA (i=128+G)
        float* rowB = out + obase + (size_t)(64 + G) * 256;   // from hB (i=192+G)
        #pragma unroll
        for (int p2 = 0; p2 < 16; ++p2) {
            const int col = (v - 16 * R4C(p2)) & 255;
            float fa = (p2 & 1) ? __high2float(hA[p2 >> 1]) : __low2float(hA[p2 >> 1]);
            float fb = (p2 & 1) ? __high2float(hB[p2 >> 1]) : __low2float(hB[p2 >> 1]);
            rowA[col] = fa * inv;
            rowB[col] = fb * inv;
        }
    }
}

extern "C" void kernel_launch(void* const* d_in, const int* in_sizes, int n_in,
                              void* d_out, int out_size, void* d_ws, size_t ws_size,
                              hipStream_t stream) {
    const float* x = (const float*)d_in[0];
    float* out = (float*)d_out;
    k_fused<<<BB, 1024, 0, stream>>>(x, out);
}

// Round 9
// 177.050 us; speedup vs baseline: 2.7246x; 2.7246x over previous
//
#include <hip/hip_runtime.h>
#include <hip/hip_fp16.h>
#include <math.h>

#define EPS 1e-20f
#define BB  512

typedef _Float16 f16x4 __attribute__((ext_vector_type(4)));
typedef float    f32x4 __attribute__((ext_vector_type(4)));

// exact builtin spelling per compiler diagnostic (round 8): ...16x16x16f16
#define MFMA16(A,B,C) __builtin_amdgcn_mfma_f32_16x16x16f16((A),(B),(C),0,0,0)

__device__ __forceinline__ float2 cmul(float2 a, float2 b){
    return make_float2(a.x*b.x - a.y*b.y, a.x*b.y + a.y*b.x);
}

// ---------------- fused kernel: one block per batch, MFMA four-step FFT ----
// 1024 threads = 16 waves; each WAVE computes one full 256-pt row per iter
// (16 rows over the t-loop). Per row:
//   G[n1][n2] = E[16n1+n2]*E[16n1+n2-i]      (gate, lane-local from LDS)
//   step1 (MFMA): C1 = G^T * W16^T  = Y^T    (sum over n1)
//   twiddle (per-lane consts): Ytw^T[n2][k1] = Y^T * W256^{k1*n2}
//   step2 (MFMA): C2 = W16 * Ytw^T = X[k2][k1]   (sum over n2)
// Fragment layouts (16x16x16_f16): A[i][k]: i=lane&15, k=4*(lane>>4)+r;
// B[k][j]: j=lane&15, k=4*(lane>>4)+r; C[i][j]: j=lane&15, i=4*(lane>>4)+r.
// -> step1's C output layout IS step2's B input layout: no transpose, no shfl,
// no bit-reversal. W16 symmetric -> same fragment serves A- and B-position.
// Round 1-7 lesson: 64-VGPR cap is immovable; live set here ~50 regs, and the
// t-loop stays `unroll 1` so the scheduler can't interleave iterations.
__global__ __launch_bounds__(1024) void k_fused(const float* __restrict__ xin,
                                                float* __restrict__ out) {
    __shared__ float2 El[256];
    __shared__ __align__(16) __half Ibuf[256 * 272];   // I * 2^-12, out-ordered
    __shared__ float wmax[16];

    const int tid  = threadIdx.x;
    const int lane = tid & 63;
    const int wv   = tid >> 6;        // wave 0..15
    const int c16  = lane & 15;       // fragment row/col index
    const int q    = lane >> 4;       // lane quadrant 0..3
    const int b    = blockIdx.x;

    // stage raw E (normalization cancels in I/max(I))
    if (tid < 256)
        El[tid] = make_float2(xin[b * 512 + tid], xin[b * 512 + 256 + tid]);
    __syncthreads();

    // ---- constant W16 fragments: W[c16][4q+r] = exp(-2pi*i*c16*(4q+r)/16) ----
    f16x4 Wr, Wi, mWi;
    #pragma unroll
    for (int r = 0; r < 4; ++r) {
        float sn, cs;
        __sincosf(-0.39269908169872414f * (float)(c16 * (4 * q + r)), &sn, &cs);
        Wr[r] = (_Float16)cs; Wi[r] = (_Float16)sn; mWi[r] = (_Float16)(-sn);
    }
    // ---- per-lane twiddle constants: f[r] = exp(-2pi*i * c16*(4q+r) / 256) ----
    float2 f0, f1, f2, f3;
    {
        float sn, cs;
        __sincosf(-0.024543692606170259f * (float)(c16 * 4 * q), &sn, &cs);
        f0 = make_float2(cs, sn);
        float2 om;
        __sincosf(-0.024543692606170259f * (float)c16, &sn, &cs);
        om = make_float2(cs, sn);
        f1 = cmul(f0, om); f2 = cmul(f1, om); f3 = cmul(f2, om);
    }

    float mx = 0.0f;
    const f32x4 zz = {0.f, 0.f, 0.f, 0.f};

    #pragma unroll 1
    for (int t = 0; t < 16; ++t) {
        const int i = 16 * t + wv;    // row index 0..255

        // ---- gate -> A fragments (A = G^T: i=n2=c16, k=n1=4q+r) ----
        f16x4 Ar, Ai;
        #pragma unroll
        for (int r = 0; r < 4; ++r) {
            int j = 16 * (4 * q + r) + c16;
            float2 g = cmul(El[j], El[(j - i) & 255]);
            Ar[r] = (_Float16)g.x;  Ai[r] = (_Float16)g.y;
        }

        // ---- step 1: C1 = G^T * W16^T = Y^T  (complex, 4 MFMA) ----
        f32x4 c1r = MFMA16(Ai, mWi, zz);  c1r = MFMA16(Ar, Wr, c1r);
        f32x4 c1i = MFMA16(Ai, Wr,  zz);  c1i = MFMA16(Ar, Wi, c1i);

        // ---- twiddle: reg r holds Y^T[n2=4q+r][k1=c16]; factor f[r] ----
        f16x4 Br, Bi;
        {
            float2 y;
            y = cmul(make_float2(c1r[0], c1i[0]), f0); Br[0]=(_Float16)y.x; Bi[0]=(_Float16)y.y;
            y = cmul(make_float2(c1r[1], c1i[1]), f1); Br[1]=(_Float16)y.x; Bi[1]=(_Float16)y.y;
            y = cmul(make_float2(c1r[2], c1i[2]), f2); Br[2]=(_Float16)y.x; Bi[2]=(_Float16)y.y;
            y = cmul(make_float2(c1r[3], c1i[3]), f3); Br[3]=(_Float16)y.x; Bi[3]=(_Float16)y.y;
        }

        // ---- step 2: C2 = W16 * Ytw^T = X[k2][k1]  (complex, 4 MFMA) ----
        f32x4 c2r = MFMA16(mWi, Bi, zz);  c2r = MFMA16(Wr, Br, c2r);
        f32x4 c2i = MFMA16(Wr,  Bi, zz);  c2i = MFMA16(Wi, Br, c2i);

        // ---- I = |X|^2 -> Ibuf (out-ordered), track fp32 max ----
        // reg r: k2 = 4q+r, k = c16 + 16*k2; shift+reverse: col = (127-k)&255
        __half* irow = Ibuf + (i ^ 128) * 272;
        #pragma unroll
        for (int r = 0; r < 4; ++r) {
            float I = c2r[r] * c2r[r] + c2i[r] * c2i[r];
            mx = fmaxf(mx, I);
            int k = c16 + 16 * (4 * q + r);
            irow[(127 - k) & 255] = __float2half_rn(I * 0.000244140625f);
        }
    }

    // ---- block-level max: wave shfl reduce -> LDS -> all threads ----
    #pragma unroll
    for (int off = 32; off; off >>= 1) mx = fmaxf(mx, __shfl_xor(mx, off, 64));
    if ((tid & 63) == 0) wmax[tid >> 6] = mx;
    __syncthreads();   // fences Ibuf and wmax
    float bm = wmax[0];
    #pragma unroll
    for (int w = 1; w < 16; ++w) bm = fmaxf(bm, wmax[w]);
    const float inv = 4096.0f / fmaxf(bm, EPS);   // undo 2^-12 and normalize

    // ---- epilogue: stream Ibuf -> out, fully coalesced (round-6 verbatim) ----
    const int l6 = tid & 63, w = tid >> 6;
    const size_t obase = ((size_t)b << 16);
    #pragma unroll 4
    for (int j = 0; j < 16; ++j) {
        const int row = 16 * j + w;
        float2 raw = *(const float2*)(Ibuf + row * 272 + 4 * l6);   // 2x half2, 8B
        float2 a = __half22float2(*(__half2*)&raw.x);
        float2 c = __half22float2(*(__half2*)&raw.y);
        float4 o = make_float4(a.x * inv, a.y * inv, c.x * inv, c.y * inv);
        *(float4*)&out[obase + 4096 * j + 4 * tid] = o;
    }
}

extern "C" void kernel_launch(void* const* d_in, const int* in_sizes, int n_in,
                              void* d_out, int out_size, void* d_ws, size_t ws_size,
                              hipStream_t stream) {
    const float* x = (const float*)d_in[0];
    float* out = (float*)d_out;
    k_fused<<<BB, 1024, 0, stream>>>(x, out);
}

// Round 10
// 160.248 us; speedup vs baseline: 3.0103x; 1.1049x over previous
//
#include <hip/hip_runtime.h>
#include <hip/hip_fp16.h>
#include <math.h>

#define EPS 1e-20f
#define BB  512

typedef _Float16 f16x4 __attribute__((ext_vector_type(4)));
typedef float    f32x4 __attribute__((ext_vector_type(4)));

#define MFMA16(A,B,C) __builtin_amdgcn_mfma_f32_16x16x16f16((A),(B),(C),0,0,0)

__device__ __forceinline__ float2 cmul(float2 a, float2 b){
    return make_float2(a.x*b.x - a.y*b.y, a.x*b.y + a.y*b.x);
}

// ---------------- fused kernel: one block per batch, MFMA four-step FFT ----
// 1024 threads = 16 waves; each WAVE computes one full 256-pt row per iter.
// Round-9 proved the MFMA pipeline (8 MFMA/row, no transpose: step1's C layout
// IS step2's B layout). This round deletes the 139KB Ibuf: compute is so cheap
// that TWO passes (pass A: max only; pass B: recompute + normalized fp32 store
// straight to global) beat one pass + LDS materialization. LDS -> 2.2KB ->
// 2 blocks/CU = 32 waves/CU, all 512 blocks co-resident, single round.
// Store coalescing: per (r) store, 64 lanes cover cols {127-c16-64q-16r}: four
// full 64B segments (no wraps) = a wave's ideal 256B footprint, just permuted.
// 64-VGPR cap (immovable, rounds 1-7): live set ~50 regs, t-loops unroll 1.
__global__ __launch_bounds__(1024) void k_fused(const float* __restrict__ xin,
                                                float* __restrict__ out) {
    __shared__ float2 El[256];
    __shared__ float wmax[16];

    const int tid  = threadIdx.x;
    const int lane = tid & 63;
    const int wv   = tid >> 6;        // wave 0..15
    const int c16  = lane & 15;       // fragment row/col index
    const int q    = lane >> 4;       // lane quadrant 0..3
    const int b    = blockIdx.x;

    // stage raw E (normalization cancels in I/max(I))
    if (tid < 256)
        El[tid] = make_float2(xin[b * 512 + tid], xin[b * 512 + 256 + tid]);
    __syncthreads();

    // ---- constant W16 fragments: W[c16][4q+r] = exp(-2pi*i*c16*(4q+r)/16) ----
    f16x4 Wr, Wi, mWi;
    #pragma unroll
    for (int r = 0; r < 4; ++r) {
        float sn, cs;
        __sincosf(-0.39269908169872414f * (float)(c16 * (4 * q + r)), &sn, &cs);
        Wr[r] = (_Float16)cs; Wi[r] = (_Float16)sn; mWi[r] = (_Float16)(-sn);
    }
    // ---- per-lane twiddle constants: f[r] = exp(-2pi*i * c16*(4q+r) / 256) ----
    float2 f0, f1, f2, f3;
    {
        float sn, cs;
        __sincosf(-0.024543692606170259f * (float)(c16 * 4 * q), &sn, &cs);
        f0 = make_float2(cs, sn);
        float2 om;
        __sincosf(-0.024543692606170259f * (float)c16, &sn, &cs);
        om = make_float2(cs, sn);
        f1 = cmul(f0, om); f2 = cmul(f1, om); f3 = cmul(f2, om);
    }

    const f32x4 zz = {0.f, 0.f, 0.f, 0.f};

    // ---- row pipeline: gate -> MFMA step1 -> twiddle -> MFMA step2 ----
    auto row_fft = [&](int i, f32x4& c2r, f32x4& c2i) {
        // gate -> A fragments (A = G^T: i=n2=c16, k=n1=4q+r)
        f16x4 Ar, Ai;
        #pragma unroll
        for (int r = 0; r < 4; ++r) {
            int j = 16 * (4 * q + r) + c16;
            float2 g = cmul(El[j], El[(j - i) & 255]);
            Ar[r] = (_Float16)g.x;  Ai[r] = (_Float16)g.y;
        }
        // step 1: C1 = G^T * W16^T = Y^T  (complex, 4 MFMA)
        f32x4 c1r = MFMA16(Ai, mWi, zz);  c1r = MFMA16(Ar, Wr, c1r);
        f32x4 c1i = MFMA16(Ai, Wr,  zz);  c1i = MFMA16(Ar, Wi, c1i);
        // twiddle: reg r holds Y^T[n2=4q+r][k1=c16]; factor f[r]
        f16x4 Br, Bi;
        {
            float2 y;
            y = cmul(make_float2(c1r[0], c1i[0]), f0); Br[0]=(_Float16)y.x; Bi[0]=(_Float16)y.y;
            y = cmul(make_float2(c1r[1], c1i[1]), f1); Br[1]=(_Float16)y.x; Bi[1]=(_Float16)y.y;
            y = cmul(make_float2(c1r[2], c1i[2]), f2); Br[2]=(_Float16)y.x; Bi[2]=(_Float16)y.y;
            y = cmul(make_float2(c1r[3], c1i[3]), f3); Br[3]=(_Float16)y.x; Bi[3]=(_Float16)y.y;
        }
        // step 2: C2 = W16 * Ytw^T = X[k2][k1]  (complex, 4 MFMA)
        c2r = MFMA16(mWi, Bi, zz);  c2r = MFMA16(Wr, Br, c2r);
        c2i = MFMA16(Wr,  Bi, zz);  c2i = MFMA16(Wi, Br, c2i);
    };

    // ---- pass A: max only, no stores ----
    float mx = 0.0f;
    #pragma unroll 1
    for (int t = 0; t < 16; ++t) {
        f32x4 c2r, c2i;
        row_fft(16 * t + wv, c2r, c2i);
        #pragma unroll
        for (int r = 0; r < 4; ++r)
            mx = fmaxf(mx, c2r[r] * c2r[r] + c2i[r] * c2i[r]);
    }

    // ---- block-level max: wave shfl reduce -> LDS -> all threads ----
    #pragma unroll
    for (int off = 32; off; off >>= 1) mx = fmaxf(mx, __shfl_xor(mx, off, 64));
    if ((tid & 63) == 0) wmax[tid >> 6] = mx;
    __syncthreads();
    float bm = wmax[0];
    #pragma unroll
    for (int w = 1; w < 16; ++w) bm = fmaxf(bm, wmax[w]);
    const float inv = 1.0f / fmaxf(bm, EPS);

    // ---- pass B: recompute, normalize, store fp32 directly (coalesced) ----
    const size_t obase = ((size_t)b << 16);
    #pragma unroll 1
    for (int t = 0; t < 16; ++t) {
        const int i = 16 * t + wv;
        f32x4 c2r, c2i;
        row_fft(i, c2r, c2i);
        float* orow = out + obase + ((size_t)(i ^ 128) << 8);
        #pragma unroll
        for (int r = 0; r < 4; ++r) {
            float I = c2r[r] * c2r[r] + c2i[r] * c2i[r];
            int k = c16 + 16 * (4 * q + r);
            orow[(127 - k) & 255] = I * inv;
        }
    }
}

extern "C" void kernel_launch(void* const* d_in, const int* in_sizes, int n_in,
                              void* d_out, int out_size, void* d_ws, size_t ws_size,
                              hipStream_t stream) {
    const float* x = (const float*)d_in[0];
    float* out = (float*)d_out;
    k_fused<<<BB, 1024, 0, stream>>>(x, out);
}

// Round 11
// 155.115 us; speedup vs baseline: 3.1099x; 1.0331x over previous
//
#include <hip/hip_runtime.h>
#include <hip/hip_fp16.h>
#include <math.h>

#define EPS 1e-20f
#define BB  512

typedef _Float16 f16x4 __attribute__((ext_vector_type(4)));
typedef float    f32x4 __attribute__((ext_vector_type(4)));

#define MFMA16(A,B,C) __builtin_amdgcn_mfma_f32_16x16x16f16((A),(B),(C),0,0,0)

__device__ __forceinline__ float2 cmul(float2 a, float2 b){
    return make_float2(a.x*b.x - a.y*b.y, a.x*b.y + a.y*b.x);
}

// ---------------- fused kernel: one block per batch, MFMA four-step FFT ----
// 1024 threads = 16 waves; each WAVE computes one full 256-pt row per iter.
// Two-pass recompute (round 10): pass A = max only, pass B = recompute +
// normalized fp32 coalesced store. LDS 2.2KB -> 2 blocks/CU, 32 waves/CU.
// THIS ROUND: hoist the i-independent gate operand El[16(4q+r)+c16] into 8
// persistent VGPRs (Edir[4]) -- it was re-read from LDS 32x per lane (both
// passes). Halves all LDS traffic (8 -> 4 ds_read_b64 per row) and the 4-way
// bank-conflict serialization. Peak live ~54 regs < the immovable 64 cap;
// t-loops stay `unroll 1` (rounds 1-7 lesson: interleave -> spill).
__global__ __launch_bounds__(1024) void k_fused(const float* __restrict__ xin,
                                                float* __restrict__ out) {
    __shared__ float2 El[256];
    __shared__ float wmax[16];

    const int tid  = threadIdx.x;
    const int lane = tid & 63;
    const int wv   = tid >> 6;        // wave 0..15
    const int c16  = lane & 15;       // fragment row/col index
    const int q    = lane >> 4;       // lane quadrant 0..3
    const int b    = blockIdx.x;

    // stage raw E (normalization cancels in I/max(I))
    if (tid < 256)
        El[tid] = make_float2(xin[b * 512 + tid], xin[b * 512 + 256 + tid]);
    __syncthreads();

    // ---- constant W16 fragments: W[c16][4q+r] = exp(-2pi*i*c16*(4q+r)/16) ----
    f16x4 Wr, Wi, mWi;
    #pragma unroll
    for (int r = 0; r < 4; ++r) {
        float sn, cs;
        __sincosf(-0.39269908169872414f * (float)(c16 * (4 * q + r)), &sn, &cs);
        Wr[r] = (_Float16)cs; Wi[r] = (_Float16)sn; mWi[r] = (_Float16)(-sn);
    }
    // ---- per-lane twiddle constants: f[r] = exp(-2pi*i * c16*(4q+r) / 256) ----
    float2 f0, f1, f2, f3;
    {
        float sn, cs;
        __sincosf(-0.024543692606170259f * (float)(c16 * 4 * q), &sn, &cs);
        f0 = make_float2(cs, sn);
        float2 om;
        __sincosf(-0.024543692606170259f * (float)c16, &sn, &cs);
        om = make_float2(cs, sn);
        f1 = cmul(f0, om); f2 = cmul(f1, om); f3 = cmul(f2, om);
    }

    // ---- hoist i-independent gate operand: Edir[r] = El[16(4q+r)+c16] ----
    float2 Edir[4];
    #pragma unroll
    for (int r = 0; r < 4; ++r)
        Edir[r] = El[16 * (4 * q + r) + c16];

    const f32x4 zz = {0.f, 0.f, 0.f, 0.f};

    // ---- row pipeline: gate -> MFMA step1 -> twiddle -> MFMA step2 ----
    auto row_fft = [&](int i, f32x4& c2r, f32x4& c2i) {
        // gate -> A fragments (A = G^T: i=n2=c16, k=n1=4q+r)
        f16x4 Ar, Ai;
        #pragma unroll
        for (int r = 0; r < 4; ++r) {
            int j = 16 * (4 * q + r) + c16;
            float2 g = cmul(Edir[r], El[(j - i) & 255]);
            Ar[r] = (_Float16)g.x;  Ai[r] = (_Float16)g.y;
        }
        // step 1: C1 = G^T * W16^T = Y^T  (complex, 4 MFMA)
        f32x4 c1r = MFMA16(Ai, mWi, zz);  c1r = MFMA16(Ar, Wr, c1r);
        f32x4 c1i = MFMA16(Ai, Wr,  zz);  c1i = MFMA16(Ar, Wi, c1i);
        // twiddle: reg r holds Y^T[n2=4q+r][k1=c16]; factor f[r]
        f16x4 Br, Bi;
        {
            float2 y;
            y = cmul(make_float2(c1r[0], c1i[0]), f0); Br[0]=(_Float16)y.x; Bi[0]=(_Float16)y.y;
            y = cmul(make_float2(c1r[1], c1i[1]), f1); Br[1]=(_Float16)y.x; Bi[1]=(_Float16)y.y;
            y = cmul(make_float2(c1r[2], c1i[2]), f2); Br[2]=(_Float16)y.x; Bi[2]=(_Float16)y.y;
            y = cmul(make_float2(c1r[3], c1i[3]), f3); Br[3]=(_Float16)y.x; Bi[3]=(_Float16)y.y;
        }
        // step 2: C2 = W16 * Ytw^T = X[k2][k1]  (complex, 4 MFMA)
        c2r = MFMA16(mWi, Bi, zz);  c2r = MFMA16(Wr, Br, c2r);
        c2i = MFMA16(Wr,  Bi, zz);  c2i = MFMA16(Wi, Br, c2i);
    };

    // ---- pass A: max only, no stores ----
    float mx = 0.0f;
    #pragma unroll 1
    for (int t = 0; t < 16; ++t) {
        f32x4 c2r, c2i;
        row_fft(16 * t + wv, c2r, c2i);
        #pragma unroll
        for (int r = 0; r < 4; ++r)
            mx = fmaxf(mx, c2r[r] * c2r[r] + c2i[r] * c2i[r]);
    }

    // ---- block-level max: wave shfl reduce -> LDS -> all threads ----
    #pragma unroll
    for (int off = 32; off; off >>= 1) mx = fmaxf(mx, __shfl_xor(mx, off, 64));
    if ((tid & 63) == 0) wmax[tid >> 6] = mx;
    __syncthreads();
    float bm = wmax[0];
    #pragma unroll
    for (int w = 1; w < 16; ++w) bm = fmaxf(bm, wmax[w]);
    const float inv = 1.0f / fmaxf(bm, EPS);

    // ---- pass B: recompute, normalize, store fp32 directly (coalesced) ----
    const size_t obase = ((size_t)b << 16);
    #pragma unroll 1
    for (int t = 0; t < 16; ++t) {
        const int i = 16 * t + wv;
        f32x4 c2r, c2i;
        row_fft(i, c2r, c2i);
        float* orow = out + obase + ((size_t)(i ^ 128) << 8);
        #pragma unroll
        for (int r = 0; r < 4; ++r) {
            float I = c2r[r] * c2r[r] + c2i[r] * c2i[r];
            int k = c16 + 16 * (4 * q + r);
            orow[(127 - k) & 255] = I * inv;
        }
    }
}

extern "C" void kernel_launch(void* const* d_in, const int* in_sizes, int n_in,
                              void* d_out, int out_size, void* d_ws, size_t ws_size,
                              hipStream_t stream) {
    const float* x = (const float*)d_in[0];
    float* out = (float*)d_out;
    k_fused<<<BB, 1024, 0, stream>>>(x, out);
}